// Round 10
// baseline (92.652 us; speedup 1.0000x reference)
//
#include <hip/hip_runtime.h>

// x[256,1,58,58] -> conv5x5(64) -> maxpool2 -> conv5x5(128) -> linear(10)
//   -> out[256,23,23,10] f32
//
// R10 = R6 (best: 61us) + in-slice load/compute phase separation:
//   all 10 A ds_reads hoisted into named regs, then all 16 B global loads,
//   then two pure-MFMA clusters (40+40) under s_setprio(1). Removes the
//   ~120cyc exposed ds_read latency per 8 MFMAs that capped MfmaUtil at 41%.
// conv2 = 16x16x32 MFMA; wave owns all 128 oc x 4-5 M-tiles; B from
// L2-resident fragment-ordered w2c; A from LDS xs (144B rows). K-loop has
// no barriers and a single uniform kk order (L2-friendly - R9 lesson).

typedef __attribute__((ext_vector_type(8))) short bf16x8;
typedef __attribute__((ext_vector_type(4))) float f32x4;
typedef __attribute__((ext_vector_type(4))) unsigned int u32x4;

#define MFMA16(a, b, c) __builtin_amdgcn_mfma_f32_16x16x32_bf16((a), (b), (c), 0, 0, 0)

static __device__ __forceinline__ unsigned short f2bf(float f) {
    unsigned u = __builtin_bit_cast(unsigned, f);
    u += 0x7FFFu + ((u >> 16) & 1u);   // RNE
    return (unsigned short)(u >> 16);
}

// ---- K0: w2[oc128][ic64][kk25] f32 -> w2c fragment order:
//   w2c[kk*8192 + nt*1024 + hf*512 + lane*8 + j]
//     = bf16( w2[(nt*16+l16)*1600 + (hf*32 + kg*8 + j)*25 + kk] )
__global__ __launch_bounds__(256) void prep_w2c(
    const float* __restrict__ w2, unsigned short* __restrict__ w2c)
{
    int t = blockIdx.x * 256 + threadIdx.x;        // 25600 entries
    if (t >= 25600) return;
    const int lane = t & 63, hf = (t >> 6) & 1, nt = (t >> 7) & 7, kk = t >> 10;
    const int l16 = lane & 15, kg = lane >> 4;
    const int oc = nt * 16 + l16;
    const int icb = hf * 32 + kg * 8;
    unsigned pk[4];
#pragma unroll
    for (int h = 0; h < 4; ++h) {
        unsigned short lo = f2bf(w2[oc * 1600 + (icb + 2 * h) * 25 + kk]);
        unsigned short hi = f2bf(w2[oc * 1600 + (icb + 2 * h + 1) * 25 + kk]);
        pk[h] = (unsigned)lo | ((unsigned)hi << 16);
    }
    u32x4 v; v.x = pk[0]; v.y = pk[1]; v.z = pk[2]; v.w = pk[3];
    *(u32x4*)(w2c + (size_t)t * 8) = v;
}

// LDS map (152320 B):
//   conv phase: xs  [0, 104976)       729 pixel rows x 144B (64 bf16 + pad)
//               xbf [104976, 111704)  58x58 input as bf16
//               w1t [111704, 115800)  [k32][oc64] bf16
//   epilogue:   econ[0, 147968)       544 sp rows x 272B
//   always:     lwT [147968, 152320)  16 o rows x 272B
#define XBF_OFF  104976
#define W1T_OFF  111704
#define ECON_STR 272
#define LWT_OFF  147968
#define LDS_TOT  152320

__global__ __launch_bounds__(512, 2) void fused_net(
    const float* __restrict__ x, const float* __restrict__ w1,
    const unsigned short* __restrict__ w2c,
    const float* __restrict__ lw, const float* __restrict__ lb,
    float* __restrict__ out)
{
    extern __shared__ char lds[];
    unsigned short* xbf = (unsigned short*)(lds + XBF_OFF);
    unsigned short* w1t = (unsigned short*)(lds + W1T_OFF);
    const int b = blockIdx.x, tid = threadIdx.x;
    const int lane = tid & 63, w = tid >> 6;        // 8 waves
    const int l16 = lane & 15, kg = lane >> 4;

    // ---- stage x -> xbf (bf16), w1 -> w1t [k][oc], lw -> lwT ----
    const float4* xg = (const float4*)(x + b * 3364);
    for (int i = tid; i < 841; i += 512) {
        float4 v = xg[i];
        unsigned p0 = (unsigned)f2bf(v.x) | ((unsigned)f2bf(v.y) << 16);
        unsigned p1 = (unsigned)f2bf(v.z) | ((unsigned)f2bf(v.w) << 16);
        *(uint2*)(xbf + i * 4) = make_uint2(p0, p1);
    }
    for (int i = tid; i < 2048; i += 512) {
        int k = i >> 6, oc = i & 63;
        w1t[i] = (k < 25) ? f2bf(w1[oc * 25 + k]) : (unsigned short)0;
    }
    for (int i = tid; i < 2048; i += 512) {
        int o = i >> 7, cc = i & 127;
        float v = (o < 10) ? lw[o * 128 + cc] : 0.f;
        *(unsigned short*)(lds + LWT_OFF + o * 272 + cc * 2) = f2bf(v);
    }
    __syncthreads();

    // ================= conv1 + maxpool -> xs =================
    {
        int koff[8];
        unsigned kmsk[8];
#pragma unroll
        for (int j = 0; j < 8; ++j) {
            int k = kg * 8 + j;
            int kh = k / 5, kw = k - 5 * kh;
            koff[j] = (k < 25) ? (kh * 58 + kw) : 0;
            kmsk[j] = (k < 25) ? 0xFFFFu : 0u;
        }
        bf16x8 bfrag[4];
#pragma unroll
        for (int ot = 0; ot < 4; ++ot)
#pragma unroll
            for (int j = 0; j < 8; ++j)
                bfrag[ot][j] = (short)w1t[(kg * 8 + j) * 64 + ot * 16 + l16];

        const f32x4 zero4 = {0.f, 0.f, 0.f, 0.f};
        for (int t = w; t < 183; t += 8) {
            int p = t * 4 + (l16 >> 2);
            if (p > 728) p = 728;
            const int q = l16 & 3;
            const int ph = p / 27, pw = p - 27 * ph;
            const int base = (2 * ph + (q >> 1)) * 58 + 2 * pw + (q & 1);
            bf16x8 afrag;
#pragma unroll
            for (int j = 0; j < 8; ++j)
                afrag[j] = (short)(xbf[base + koff[j]] & kmsk[j]);
            f32x4 acc1[4];
#pragma unroll
            for (int ot = 0; ot < 4; ++ot)
                acc1[ot] = MFMA16(afrag, bfrag[ot], zero4);
            const int pout = t * 4 + kg;
            if (pout < 729) {
#pragma unroll
                for (int ot = 0; ot < 4; ++ot) {
                    float m = fmaxf(fmaxf(acc1[ot][0], acc1[ot][1]),
                                    fmaxf(acc1[ot][2], acc1[ot][3]));
                    *(unsigned short*)(lds + pout * 144 + (ot * 16 + l16) * 2)
                        = f2bf(m);
                }
            }
        }
    }
    __syncthreads();   // xs complete; conv1 scratch (xbf/w1t) now dead

    // ========== conv2: barrier-free K-loop, phase-separated slices ==========
    // 34 tiles of 16 rows: tile t<33 starts at 16t; tile 33 starts at 513.
    // Wave w owns tiles {w, w+8, w+16, w+24 (,w+32 if <34)}.
    const int mtc = (w < 2) ? 5 : 4;
    int abase[5];
#pragma unroll
    for (int ti = 0; ti < 5; ++ti) {
        int tile = w + 8 * ti;
        if (tile > 33) tile = w;               // unused slot (w>=2), safe addr
        const int tstart = (tile == 33) ? 513 : tile * 16;
        const int sp = tstart + l16;
        const int oh = sp / 23, ow = sp - oh * 23;
        abase[ti] = (oh * 27 + ow) * 144 + kg * 16;
    }

    f32x4 acc[5][8];
#pragma unroll
    for (int ti = 0; ti < 5; ++ti)
#pragma unroll
        for (int nt = 0; nt < 8; ++nt)
            acc[ti][nt] = (f32x4){0.f, 0.f, 0.f, 0.f};

    for (int kk = 0; kk < 25; ++kk) {
        const int kh = kk / 5, kw = kk - 5 * kh;
        const int pixoff = (kh * 27 + kw) * 144;

        // phase 1: ALL A-frag ds_reads (10, independent) into named regs
        bf16x8 A0[5], A1[5];
#pragma unroll
        for (int ti = 0; ti < 5; ++ti) {
            const char* ap = lds + abase[ti] + pixoff;
            A0[ti] = *(const bf16x8*)(ap);
            A1[ti] = *(const bf16x8*)(ap + 64);
        }
        // phase 2: ALL B-frag global loads (16, L2/L1-resident stream)
        const unsigned short* wp = w2c + (size_t)kk * 8192 + lane * 8;
        bf16x8 B0[8], B1[8];
#pragma unroll
        for (int nt = 0; nt < 8; ++nt)
            B0[nt] = *(const bf16x8*)(wp + nt * 1024);
#pragma unroll
        for (int nt = 0; nt < 8; ++nt)
            B1[nt] = *(const bf16x8*)(wp + nt * 1024 + 512);

        // phase 3: pure-MFMA clusters (no memory ops interleaved)
        __builtin_amdgcn_s_setprio(1);
#pragma unroll
        for (int ti = 0; ti < 5; ++ti) {
            if (ti < mtc) {
#pragma unroll
                for (int nt = 0; nt < 8; ++nt)
                    acc[ti][nt] = MFMA16(A0[ti], B0[nt], acc[ti][nt]);
            }
        }
#pragma unroll
        for (int ti = 0; ti < 5; ++ti) {
            if (ti < mtc) {
#pragma unroll
                for (int nt = 0; nt < 8; ++nt)
                    acc[ti][nt] = MFMA16(A1[ti], B1[nt], acc[ti][nt]);
            }
        }
        __builtin_amdgcn_s_setprio(0);
    }

    // ================= epilogue: econ bf16 + linear MFMA =================
    __syncthreads();   // all waves done reading xs before econ overwrites it
#pragma unroll
    for (int ti = 0; ti < 5; ++ti) {
        if (ti < mtc) {
            int tile = w + 8 * ti;
            if (tile > 33) tile = w;
            const int rbase = ((tile == 33) ? 513 : tile * 16) + kg * 4;
#pragma unroll
            for (int nt = 0; nt < 8; ++nt) {
                const int col = nt * 16 + l16;
#pragma unroll
                for (int r = 0; r < 4; ++r)
                    *(unsigned short*)(lds + (rbase + r) * ECON_STR + col * 2)
                        = f2bf(acc[ti][nt][r]);
            }
        }
    }
    __syncthreads();

    const float lbv = (l16 < 10) ? lb[l16] : 0.f;
#pragma unroll
    for (int i = 0; i < 5; ++i) {
        const int t = w + 8 * i;
        if (t < 34) {
            f32x4 al = {0.f, 0.f, 0.f, 0.f};
            const char* arow = lds + (t * 16 + l16) * ECON_STR + kg * 16;
            const char* brow = lds + LWT_OFF + l16 * 272 + kg * 16;
#pragma unroll
            for (int ks = 0; ks < 4; ++ks) {
                bf16x8 av = *(const bf16x8*)(arow + ks * 64);
                bf16x8 bv = *(const bf16x8*)(brow + ks * 64);
                al = MFMA16(av, bv, al);
            }
            if (l16 < 10) {
#pragma unroll
                for (int r = 0; r < 4; ++r) {
                    int sp = t * 16 + kg * 4 + r;
                    if (sp < 529)
                        out[((size_t)b * 529 + sp) * 10 + l16] = al[r] + lbv;
                }
            }
        }
    }
}

extern "C" void kernel_launch(void* const* d_in, const int* in_sizes, int n_in,
                              void* d_out, int out_size, void* d_ws, size_t ws_size,
                              hipStream_t stream) {
    const float* x  = (const float*)d_in[0];
    const float* w1 = (const float*)d_in[1];
    const float* w2 = (const float*)d_in[2];
    const float* lw = (const float*)d_in[3];
    const float* lb = (const float*)d_in[4];
    float* out = (float*)d_out;

    unsigned short* w2c = (unsigned short*)d_ws;   // 400 KB fragment-ordered

    (void)hipFuncSetAttribute((const void*)fused_net,
                              hipFuncAttributeMaxDynamicSharedMemorySize,
                              LDS_TOT);

    prep_w2c<<<100, 256, 0, stream>>>(w2, w2c);
    fused_net<<<256, 512, LDS_TOT, stream>>>(x, w1, w2c, lw, lb, out);
}

// Round 11
// 66.789 us; speedup vs baseline: 1.3872x; 1.3872x over previous
//
#include <hip/hip_runtime.h>

// x[256,1,58,58] -> conv5x5(64) -> maxpool2 -> conv5x5(128) -> linear(10)
//   -> out[256,23,23,10] f32
//
// R11 = R6 structure (best: 61us) at 16 waves / 1024 threads, 1 block/CU:
//   4 waves/SIMD so the SIMD scheduler interleaves MFMA / LDS-A / L1-B pipes
//   across waves (m114 mechanism) instead of serializing them at 2 waves/SIMD.
//   Wave = (mgrp 0-7) x (ngrp 0-1): 4-5 M-tiles x 64 oc -> acc 80 VGPR,
//   B 4 frags/hf from L2-resident w2c, A 1 ds_read_b128 per (tile,hf).
//   Plain interleaved code (R10 lesson: never hand-hoist; compiler schedules).

typedef __attribute__((ext_vector_type(8))) short bf16x8;
typedef __attribute__((ext_vector_type(4))) float f32x4;
typedef __attribute__((ext_vector_type(4))) unsigned int u32x4;

#define MFMA16(a, b, c) __builtin_amdgcn_mfma_f32_16x16x32_bf16((a), (b), (c), 0, 0, 0)

static __device__ __forceinline__ unsigned short f2bf(float f) {
    unsigned u = __builtin_bit_cast(unsigned, f);
    u += 0x7FFFu + ((u >> 16) & 1u);   // RNE
    return (unsigned short)(u >> 16);
}

// ---- K0: w2[oc128][ic64][kk25] f32 -> w2c fragment order:
//   w2c[kk*8192 + nt*1024 + hf*512 + lane*8 + j]
//     = bf16( w2[(nt*16+l16)*1600 + (hf*32 + kg*8 + j)*25 + kk] )
__global__ __launch_bounds__(256) void prep_w2c(
    const float* __restrict__ w2, unsigned short* __restrict__ w2c)
{
    int t = blockIdx.x * 256 + threadIdx.x;        // 25600 entries
    if (t >= 25600) return;
    const int lane = t & 63, hf = (t >> 6) & 1, nt = (t >> 7) & 7, kk = t >> 10;
    const int l16 = lane & 15, kg = lane >> 4;
    const int oc = nt * 16 + l16;
    const int icb = hf * 32 + kg * 8;
    unsigned pk[4];
#pragma unroll
    for (int h = 0; h < 4; ++h) {
        unsigned short lo = f2bf(w2[oc * 1600 + (icb + 2 * h) * 25 + kk]);
        unsigned short hi = f2bf(w2[oc * 1600 + (icb + 2 * h + 1) * 25 + kk]);
        pk[h] = (unsigned)lo | ((unsigned)hi << 16);
    }
    u32x4 v; v.x = pk[0]; v.y = pk[1]; v.z = pk[2]; v.w = pk[3];
    *(u32x4*)(w2c + (size_t)t * 8) = v;
}

// LDS map (152320 B):
//   conv phase: xs  [0, 104976)       729 pixel rows x 144B (64 bf16 + pad)
//               xbf [104976, 111704)  58x58 input as bf16
//               w1t [111704, 115800)  [k32][oc64] bf16
//   epilogue:   econ[0, 147968)       544 sp rows x 272B
//   always:     lwT [147968, 152320)  16 o rows x 272B
#define XBF_OFF  104976
#define W1T_OFF  111704
#define ECON_STR 272
#define LWT_OFF  147968
#define LDS_TOT  152320

__global__ __launch_bounds__(1024, 4) void fused_net(
    const float* __restrict__ x, const float* __restrict__ w1,
    const unsigned short* __restrict__ w2c,
    const float* __restrict__ lw, const float* __restrict__ lb,
    float* __restrict__ out)
{
    extern __shared__ char lds[];
    unsigned short* xbf = (unsigned short*)(lds + XBF_OFF);
    unsigned short* w1t = (unsigned short*)(lds + W1T_OFF);
    const int b = blockIdx.x, tid = threadIdx.x;
    const int lane = tid & 63, w = tid >> 6;        // 16 waves
    const int l16 = lane & 15, kg = lane >> 4;
    const int mgrp = w >> 1, ngrp = w & 1;          // 8 x 2

    // ---- stage x -> xbf (bf16), w1 -> w1t [k][oc], lw -> lwT ----
    const float4* xg = (const float4*)(x + b * 3364);
    for (int i = tid; i < 841; i += 1024) {
        float4 v = xg[i];
        unsigned p0 = (unsigned)f2bf(v.x) | ((unsigned)f2bf(v.y) << 16);
        unsigned p1 = (unsigned)f2bf(v.z) | ((unsigned)f2bf(v.w) << 16);
        *(uint2*)(xbf + i * 4) = make_uint2(p0, p1);
    }
    for (int i = tid; i < 2048; i += 1024) {
        int k = i >> 6, oc = i & 63;
        w1t[i] = (k < 25) ? f2bf(w1[oc * 25 + k]) : (unsigned short)0;
    }
    for (int i = tid; i < 2048; i += 1024) {
        int o = i >> 7, cc = i & 127;
        float v = (o < 10) ? lw[o * 128 + cc] : 0.f;
        *(unsigned short*)(lds + LWT_OFF + o * 272 + cc * 2) = f2bf(v);
    }
    __syncthreads();

    // ================= conv1 + maxpool -> xs =================
    {
        int koff[8];
        unsigned kmsk[8];
#pragma unroll
        for (int j = 0; j < 8; ++j) {
            int k = kg * 8 + j;
            int kh = k / 5, kw = k - 5 * kh;
            koff[j] = (k < 25) ? (kh * 58 + kw) : 0;
            kmsk[j] = (k < 25) ? 0xFFFFu : 0u;
        }
        bf16x8 bfrag[4];
#pragma unroll
        for (int ot = 0; ot < 4; ++ot)
#pragma unroll
            for (int j = 0; j < 8; ++j)
                bfrag[ot][j] = (short)w1t[(kg * 8 + j) * 64 + ot * 16 + l16];

        const f32x4 zero4 = {0.f, 0.f, 0.f, 0.f};
        for (int t = w; t < 183; t += 16) {
            int p = t * 4 + (l16 >> 2);
            if (p > 728) p = 728;
            const int q = l16 & 3;
            const int ph = p / 27, pw = p - 27 * ph;
            const int base = (2 * ph + (q >> 1)) * 58 + 2 * pw + (q & 1);
            bf16x8 afrag;
#pragma unroll
            for (int j = 0; j < 8; ++j)
                afrag[j] = (short)(xbf[base + koff[j]] & kmsk[j]);
            f32x4 acc1[4];
#pragma unroll
            for (int ot = 0; ot < 4; ++ot)
                acc1[ot] = MFMA16(afrag, bfrag[ot], zero4);
            const int pout = t * 4 + kg;
            if (pout < 729) {
#pragma unroll
                for (int ot = 0; ot < 4; ++ot) {
                    float m = fmaxf(fmaxf(acc1[ot][0], acc1[ot][1]),
                                    fmaxf(acc1[ot][2], acc1[ot][3]));
                    *(unsigned short*)(lds + pout * 144 + (ot * 16 + l16) * 2)
                        = f2bf(m);
                }
            }
        }
    }
    __syncthreads();   // xs complete; conv1 scratch (xbf/w1t) now dead

    // ====== conv2: barrier-free K-loop, wave = 4-5 M-tiles x 64 oc ======
    // 34 tiles of 16 rows: tile t<33 starts at 16t; tile 33 starts at 513.
    // mgrp m owns tiles {m, m+8, m+16, m+24 (, m+32 if m<2)}.
    const int mtc = (mgrp < 2) ? 5 : 4;
    int abase[5];
#pragma unroll
    for (int ti = 0; ti < 5; ++ti) {
        int tile = mgrp + 8 * ti;
        if (tile > 33) tile = mgrp;            // unused slot, safe addr
        const int tstart = (tile == 33) ? 513 : tile * 16;
        const int sp = tstart + l16;
        const int oh = sp / 23, ow = sp - oh * 23;
        abase[ti] = (oh * 27 + ow) * 144 + kg * 16;
    }

    f32x4 acc[5][4];
#pragma unroll
    for (int ti = 0; ti < 5; ++ti)
#pragma unroll
        for (int nt = 0; nt < 4; ++nt)
            acc[ti][nt] = (f32x4){0.f, 0.f, 0.f, 0.f};

    for (int kk = 0; kk < 25; ++kk) {
        const int kh = kk / 5, kw = kk - 5 * kh;
        const int pixoff = (kh * 27 + kw) * 144;
        const unsigned short* wp =
            w2c + (size_t)kk * 8192 + (ngrp * 4) * 1024 + lane * 8;
#pragma unroll
        for (int hf = 0; hf < 2; ++hf) {
            bf16x8 Bf[4];
#pragma unroll
            for (int j = 0; j < 4; ++j)
                Bf[j] = *(const bf16x8*)(wp + j * 1024 + hf * 512);
#pragma unroll
            for (int ti = 0; ti < 5; ++ti) {
                if (ti < mtc) {
                    bf16x8 a =
                        *(const bf16x8*)(lds + abase[ti] + pixoff + hf * 64);
#pragma unroll
                    for (int j = 0; j < 4; ++j)
                        acc[ti][j] = MFMA16(a, Bf[j], acc[ti][j]);
                }
            }
        }
    }

    // ================= epilogue: econ bf16 + linear MFMA =================
    __syncthreads();   // all waves done reading xs before econ overwrites it
#pragma unroll
    for (int ti = 0; ti < 5; ++ti) {
        if (ti < mtc) {
            int tile = mgrp + 8 * ti;
            if (tile > 33) tile = mgrp;
            const int rbase = ((tile == 33) ? 513 : tile * 16) + kg * 4;
#pragma unroll
            for (int j = 0; j < 4; ++j) {
                const int col = (ngrp * 4 + j) * 16 + l16;
#pragma unroll
                for (int r = 0; r < 4; ++r)
                    *(unsigned short*)(lds + (rbase + r) * ECON_STR + col * 2)
                        = f2bf(acc[ti][j][r]);
            }
        }
    }
    __syncthreads();

    const float lbv = (l16 < 10) ? lb[l16] : 0.f;
#pragma unroll
    for (int i = 0; i < 3; ++i) {
        const int t = w + 16 * i;
        if (t < 34) {
            f32x4 al = {0.f, 0.f, 0.f, 0.f};
            const char* arow = lds + (t * 16 + l16) * ECON_STR + kg * 16;
            const char* brow = lds + LWT_OFF + l16 * 272 + kg * 16;
#pragma unroll
            for (int ks = 0; ks < 4; ++ks) {
                bf16x8 av = *(const bf16x8*)(arow + ks * 64);
                bf16x8 bv = *(const bf16x8*)(brow + ks * 64);
                al = MFMA16(av, bv, al);
            }
            if (l16 < 10) {
#pragma unroll
                for (int r = 0; r < 4; ++r) {
                    int sp = t * 16 + kg * 4 + r;
                    if (sp < 529)
                        out[((size_t)b * 529 + sp) * 10 + l16] = al[r] + lbv;
                }
            }
        }
    }
}

extern "C" void kernel_launch(void* const* d_in, const int* in_sizes, int n_in,
                              void* d_out, int out_size, void* d_ws, size_t ws_size,
                              hipStream_t stream) {
    const float* x  = (const float*)d_in[0];
    const float* w1 = (const float*)d_in[1];
    const float* w2 = (const float*)d_in[2];
    const float* lw = (const float*)d_in[3];
    const float* lb = (const float*)d_in[4];
    float* out = (float*)d_out;

    unsigned short* w2c = (unsigned short*)d_ws;   // 400 KB fragment-ordered

    (void)hipFuncSetAttribute((const void*)fused_net,
                              hipFuncAttributeMaxDynamicSharedMemorySize,
                              LDS_TOT);

    prep_w2c<<<100, 256, 0, stream>>>(w2, w2c);
    fused_net<<<256, 1024, LDS_TOT, stream>>>(x, w1, w2c, lw, lb, out);
}